// Round 1
// 89.081 us; speedup vs baseline: 1.0032x; 1.0032x over previous
//
#include <hip/hip_runtime.h>
#include <hip/hip_bf16.h>

#define NROWS 4096
#define DDIM  256
#define EPS   1e-8f
// Normalized rows are scaled by sqrt(2*log2(e)) so the MFMA dot product IS the
// exp2 argument: exp2(<se_i, se_j>) = exp(<e_i,e_j>/T), T = 0.5.
#define SCALE 1.69864944f
#define LN2   0.69314718056f

#define NJ 32          // j-slices (grid.y)
#define JS 256         // cols per slice
#define BT 64          // cols per staged LDS chunk
#define CH (JS / BT)   // 4 chunks per slice
// LDS fragment-ordered: [buf][cgrp(4)][ks(8)][lane(64)][8 shorts] = 32 KB/buf
#define BUFSH (4 * 8 * 64 * 8)

typedef __attribute__((ext_vector_type(8))) short short8;
typedef __attribute__((ext_vector_type(4))) float f32x4;

#if __has_builtin(__builtin_amdgcn_exp2f)
#define EXP2F(x) __builtin_amdgcn_exp2f(x)
#else
#define EXP2F(x) exp2f(x)
#endif

// Compiler-level memory fence (no instructions emitted; SIInsertWaitcnts
// attaches no waits to an empty asm). Raw s_barrier does NOT get the
// vmcnt(0)/lgkmcnt(0) drain that __syncthreads forces — that drain was the
// per-chunk stall (guide §5.5 T3/T4: counted vmcnt, never 0 in main loop).
#define CFENCE() asm volatile("" ::: "memory")
#define BARRIER() do { CFENCE(); __builtin_amdgcn_s_barrier(); CFENCE(); } while (0)

__device__ __forceinline__ unsigned short f2bf(float x) {
    union { __hip_bfloat16 h; unsigned short u; } c;
    c.h = __float2bfloat16(x);
    return c.u;
}

// ---------------------------------------------------------------------------
// Kernel 1: row L2-normalize fp32 -> scaled bf16; zero S.
// One wave per row: grid = 2N/4 blocks x 256 threads.
__global__ void normalize_kernel(const float* __restrict__ a,
                                 const float* __restrict__ b,
                                 unsigned short* __restrict__ en,
                                 float* __restrict__ S, int N) {
    const int wave = threadIdx.x >> 6, lane = threadIdx.x & 63;
    const int row = blockIdx.x * 4 + wave;
    const float* src = (row < N) ? (a + (size_t)row * DDIM)
                                 : (b + (size_t)(row - N) * DDIM);
    const float4 v = reinterpret_cast<const float4*>(src)[lane];
    float ss = v.x * v.x + v.y * v.y + v.z * v.z + v.w * v.w;
    #pragma unroll
    for (int off = 32; off > 0; off >>= 1) ss += __shfl_xor(ss, off);
    const float inv = SCALE / fmaxf(sqrtf(ss), EPS * SCALE);
    ushort4 o;
    o.x = f2bf(v.x * inv);
    o.y = f2bf(v.y * inv);
    o.z = f2bf(v.z * inv);
    o.w = f2bf(v.w * inv);
    *reinterpret_cast<ushort4*>(en + (size_t)row * DDIM + lane * 4) = o;
    if (lane == 0 && row < N) S[row] = 0.0f;
}

// ---------------------------------------------------------------------------
// Kernel 2: masked exp row-sums via MFMA.
// grid = (16 i-blocks of 256 rows, NJ j-slices), block = 256 (4 waves).
// Each wave holds 64 A-rows register-resident (128 VGPRs); B staged in
// double-buffered LDS via async global_load_lds (fragment order, lane*16B).
// Schedule (T3/T4-lite): per chunk
//   [lgkmcnt(0); s_barrier]  -> readers of the buffer being re-staged are done
//   issue stage(c+1)         -> 8 global_load_lds stay IN FLIGHT
//   s_waitcnt vmcnt(8)       -> own chunk-c loads landed (8 newest still out)
//   [s_barrier]              -> all waves' chunk-c data visible
//   compute chunk c (setprio(1) around MFMA cluster, T5)
// No vmcnt(0) drain in the main loop (only at the last chunk).
// MFMA 16x16x32 bf16 verified layouts:
//   A/B operand: elem j of lane l = M[base + (l&15)][ks*32 + (l>>4)*8 + j]
//   C/D:         reg r of lane l  = C[(l>>4)*4 + r][l&15]
__global__ __launch_bounds__(256, 2) void simsum_kernel(
        const short* __restrict__ en,
        float* __restrict__ S,
        float* __restrict__ pos) {
    __shared__ short bt[2 * BUFSH];
    const int tid = threadIdx.x;
    const int wave = tid >> 6, lane = tid & 63;
    const int lrow = lane & 15, quad = lane >> 4;
    const int i0 = blockIdx.x * 256 + wave * 64;
    const int jb = blockIdx.y * JS;

    // A fragments: 4 row-tiles x K=256, loaded once.
    short8 afrag[4][8];
    #pragma unroll
    for (int t = 0; t < 4; ++t)
        #pragma unroll
        for (int ks = 0; ks < 8; ++ks)
            afrag[t][ks] = *reinterpret_cast<const short8*>(
                en + (size_t)(i0 + t * 16 + lrow) * DDIM + ks * 32 + quad * 8);

    float rowsum[4][4];
    #pragma unroll
    for (int t = 0; t < 4; ++t)
        #pragma unroll
        for (int r = 0; r < 4; ++r) rowsum[t][r] = 0.0f;

    // Async stage of one 64-col chunk: wave w stages row-group w (16 cols),
    // all 8 k-steps. DMA writes LDS at uniform base + lane*16B, which is
    // exactly fragment order for the consuming ds_read_b128.
    auto stage = [&](int jc, int buf) {
        const short* g = en + (size_t)(jc + wave * 16 + lrow) * DDIM + quad * 8;
        short* l = bt + buf * BUFSH + wave * 4096;
        #pragma unroll
        for (int ks = 0; ks < 8; ++ks) {
            __builtin_amdgcn_global_load_lds(
                (const __attribute__((address_space(1))) void*)(g + ks * 32),
                (__attribute__((address_space(3))) void*)(l + ks * 512),
                16, 0, 0);
        }
    };

    stage(jb, 0);
    for (int c = 0; c < CH; ++c) {
        // Barrier A: all waves' ds_reads of the buffer stage(c+1) will
        // overwrite have been DELIVERED (lgkmcnt(0)) and consumed.
        asm volatile("s_waitcnt lgkmcnt(0)" ::: "memory");
        BARRIER();
        if (c + 1 < CH) {
            stage(jb + (c + 1) * BT, (c + 1) & 1);
            asm volatile("s_waitcnt vmcnt(8)" ::: "memory");  // chunk c landed
        } else {
            asm volatile("s_waitcnt vmcnt(0)" ::: "memory");  // final chunk
        }
        __builtin_amdgcn_sched_barrier(0);
        BARRIER();                       // Barrier B: chunk c visible to all
        const short* lb = bt + (c & 1) * BUFSH;
        #pragma unroll
        for (int cg = 0; cg < 4; ++cg) {
            f32x4 acc[4];
            #pragma unroll
            for (int t = 0; t < 4; ++t) acc[t] = f32x4{0.f, 0.f, 0.f, 0.f};
            __builtin_amdgcn_s_setprio(1);
            #pragma unroll
            for (int ks = 0; ks < 8; ++ks) {
                const short8 bfrag = *reinterpret_cast<const short8*>(
                    lb + cg * 4096 + ks * 512 + lane * 8);
                #pragma unroll
                for (int t = 0; t < 4; ++t)
                    acc[t] = __builtin_amdgcn_mfma_f32_16x16x32_bf16(
                        afrag[t][ks], bfrag, acc[t], 0, 0, 0);
            }
            __builtin_amdgcn_s_setprio(0);
            const int col = jb + c * BT + cg * 16 + lrow;
            const int cm = col & (NROWS - 1);
            #pragma unroll
            for (int t = 0; t < 4; ++t) {
                #pragma unroll
                for (int r = 0; r < 4; ++r)
                    rowsum[t][r] += EXP2F(acc[t][r]);
                const unsigned delta = (unsigned)(cm - (i0 + t * 16 + quad * 4));
                if (delta < 4u) {              // diagonal-family cell (rare)
                    const float d = (delta == 0) ? acc[t][0]
                                  : (delta == 1) ? acc[t][1]
                                  : (delta == 2) ? acc[t][2]
                                  :                acc[t][3];
                    const float ed = EXP2F(d);
                    #pragma unroll
                    for (int r = 0; r < 4; ++r)
                        if (r == (int)delta) rowsum[t][r] -= ed;
                    if (col >= NROWS) pos[cm] = d * LN2;  // positive_sim
                }
            }
        }
    }

    // Reduce each rowsum over the 16 lanes sharing a quad, then one atomic.
    #pragma unroll
    for (int t = 0; t < 4; ++t) {
        #pragma unroll
        for (int r = 0; r < 4; ++r) {
            float v = rowsum[t][r];
            v += __shfl_xor(v, 1);
            v += __shfl_xor(v, 2);
            v += __shfl_xor(v, 4);
            v += __shfl_xor(v, 8);
            rowsum[t][r] = v;
        }
        if (lrow < 4) {
            const float v = (lrow == 0) ? rowsum[t][0]
                          : (lrow == 1) ? rowsum[t][1]
                          : (lrow == 2) ? rowsum[t][2]
                          :               rowsum[t][3];
            atomicAdd(&S[i0 + t * 16 + quad * 4 + lrow], v);
        }
    }
}

// ---------------------------------------------------------------------------
// Kernel 3: loss = -(1/N) * sum_i (pos[i] - log(S[i])). One block x 1024.
// float4 loads: each thread owns 4 consecutive rows.
__global__ void loss_kernel(const float* __restrict__ S,
                            const float* __restrict__ pos,
                            float* __restrict__ out, int N) {
    const int i = threadIdx.x * 4;
    float acc = 0.0f;
    if (i < N) {
        const float4 s4 = *reinterpret_cast<const float4*>(S + i);
        const float4 p4 = *reinterpret_cast<const float4*>(pos + i);
        acc = (p4.x - __logf(s4.x)) + (p4.y - __logf(s4.y)) +
              (p4.z - __logf(s4.z)) + (p4.w - __logf(s4.w));
    }
    #pragma unroll
    for (int off = 32; off > 0; off >>= 1) acc += __shfl_xor(acc, off);
    __shared__ float wsum[16];
    const int wave = threadIdx.x >> 6, lane = threadIdx.x & 63;
    if (lane == 0) wsum[wave] = acc;
    __syncthreads();
    if (threadIdx.x == 0) {
        float tot = 0.0f;
        #pragma unroll
        for (int w = 0; w < 16; ++w) tot += wsum[w];
        out[0] = -tot / (float)N;
    }
}

// ---------------------------------------------------------------------------
extern "C" void kernel_launch(void* const* d_in, const int* in_sizes, int n_in,
                              void* d_out, int out_size, void* d_ws, size_t ws_size,
                              hipStream_t stream) {
    const float* a = (const float*)d_in[0];
    const float* b = (const float*)d_in[1];
    float* out = (float*)d_out;
    const int N = NROWS;

    char* ws = (char*)d_ws;
    unsigned short* en = (unsigned short*)ws;                  // 2N*D*2 = 4 MB
    float* S = (float*)(ws + (size_t)2 * N * DDIM * sizeof(unsigned short));
    float* pos = S + N;

    normalize_kernel<<<(2 * N) / 4, 256, 0, stream>>>(a, b, en, S, N);
    simsum_kernel<<<dim3(N / 256, NJ), 256, 0, stream>>>((const short*)en, S, pos);
    loss_kernel<<<1, 1024, 0, stream>>>(S, pos, out, N);
}